// Round 1
// baseline (87.888 us; speedup 1.0000x reference)
//
#include <hip/hip_runtime.h>

// Oja's rule scan: B=8, T=64, N_IN=N_OUT=1024, lr = 1/1024.
// Each output row W[b,o,:] evolves independently:
//   pre = dot(W_row, x_t); y = sigmoid(pre)
//   W_row = W_row*(1 - lr*y^2) + (lr*y)*x_t
//   out[b,t,o] = y
// W is never written back -> keep it in registers for the whole scan.
// One wave (64 lanes) per row; 16 W floats per lane (4x float4).

#define BB 8
#define TT 64
#define NI 1024
#define NO 1024
#define WAVES_PER_BLOCK 4

__global__ __launch_bounds__(256, 8)
void oja_scan_kernel(const float* __restrict__ X,      // [B][T][NI]
                     const float* __restrict__ W0,     // [B][NO][NI]
                     float* __restrict__ out)          // [B][T][NO]
{
    const int lane = threadIdx.x & 63;
    const int wave = threadIdx.x >> 6;
    const int row  = blockIdx.x * WAVES_PER_BLOCK + wave;  // 0..8191
    const int b = row >> 10;          // row / 1024
    const int o = row & 1023;         // row % 1024

    const float* __restrict__ Wrow = W0 + ((size_t)b * NO + o) * NI;
    const float* __restrict__ Xb   = X  + (size_t)b * TT * NI;
    float* __restrict__ outb       = out + (size_t)b * TT * NO;

    // Lane l holds W elements at indices k*256 + l*4 + j  (k=0..3, j=0..3).
    float4 w[4];
#pragma unroll
    for (int k = 0; k < 4; ++k)
        w[k] = *reinterpret_cast<const float4*>(Wrow + k * 256 + lane * 4);

    const float lr = 1.0f / 1024.0f;

    for (int t = 0; t < TT; ++t) {
        const float* __restrict__ xt = Xb + t * NI;
        float4 x[4];
#pragma unroll
        for (int k = 0; k < 4; ++k)
            x[k] = *reinterpret_cast<const float4*>(xt + k * 256 + lane * 4);

        // partial dot product (16 elements per lane)
        float p = 0.0f;
#pragma unroll
        for (int k = 0; k < 4; ++k) {
            p = fmaf(w[k].x, x[k].x, p);
            p = fmaf(w[k].y, x[k].y, p);
            p = fmaf(w[k].z, x[k].z, p);
            p = fmaf(w[k].w, x[k].w, p);
        }

        // wave64 butterfly reduction
#pragma unroll
        for (int off = 32; off >= 1; off >>= 1)
            p += __shfl_xor(p, off, 64);

        const float y  = 1.0f / (1.0f + __expf(-p));
        const float c2 = lr * y;          // lr*y
        const float c1 = 1.0f - c2 * y;   // 1 - lr*y^2

        // W = W*c1 + c2*x
#pragma unroll
        for (int k = 0; k < 4; ++k) {
            w[k].x = fmaf(x[k].x, c2, w[k].x * c1);
            w[k].y = fmaf(x[k].y, c2, w[k].y * c1);
            w[k].z = fmaf(x[k].z, c2, w[k].z * c1);
            w[k].w = fmaf(x[k].w, c2, w[k].w * c1);
        }

        if (lane == 0)
            outb[t * NO + o] = y;
    }
}

extern "C" void kernel_launch(void* const* d_in, const int* in_sizes, int n_in,
                              void* d_out, int out_size, void* d_ws, size_t ws_size,
                              hipStream_t stream) {
    const float* X  = (const float*)d_in[0];   // [8][64][1024]
    const float* W0 = (const float*)d_in[1];   // [8][1024][1024]
    float* out = (float*)d_out;                // [8][64][1024]

    const int total_rows = BB * NO;                       // 8192
    const int blocks = total_rows / WAVES_PER_BLOCK;      // 2048
    oja_scan_kernel<<<blocks, WAVES_PER_BLOCK * 64, 0, stream>>>(X, W0, out);
}

// Round 2
// 78.971 us; speedup vs baseline: 1.1129x; 1.1129x over previous
//
#include <hip/hip_runtime.h>

// Oja's rule scan: B=8, T=64, N_IN=N_OUT=1024, lr = 1/1024.
// Row recurrence per (b,o):
//   pre = dot(W_row, x_t); y = sigmoid(pre)
//   W_row = W_row*(1 - lr*y^2) + (lr*y)*x_t ;  out[b,t,o] = y
// W lives in registers (16 floats/lane as 4x float4, one wave per row).
// Round-2 change: 8 rows (8 waves, 512 thr) per block share x_t via LDS,
// double-buffered: issue global load of x_{t+1} BEFORE step-t compute,
// write it to the other LDS buffer after, one barrier per step.
// Cuts L2 x-traffic 8x (2 GB -> 250 MB).

#define BB 8
#define TT 64
#define NI 1024
#define NO 1024
#define ROWS_PER_BLOCK 8   // 8 waves per block, one row each

__global__ __launch_bounds__(512, 8)
void oja_scan_kernel(const float* __restrict__ X,      // [B][T][NI]
                     const float* __restrict__ W0,     // [B][NO][NI]
                     float* __restrict__ out)          // [B][T][NO]
{
    __shared__ float xbuf[2][NI];   // 8 KB, double-buffered x_t

    const int tid  = threadIdx.x;
    const int lane = tid & 63;
    const int wave = tid >> 6;
    const int row  = blockIdx.x * ROWS_PER_BLOCK + wave;  // 0..8191
    const int b = row >> 10;          // 128 blocks per batch: blocks never straddle b
    const int o = row & 1023;

    const float* __restrict__ Wrow = W0 + ((size_t)b * NO + o) * NI;
    const float* __restrict__ Xb   = X  + (size_t)b * TT * NI;
    float* __restrict__ outb       = out + (size_t)b * TT * NO;

    // Lane l holds W elements at indices k*256 + l*4 + j  (k=0..3, j=0..3).
    float4 w[4];
#pragma unroll
    for (int k = 0; k < 4; ++k)
        w[k] = *reinterpret_cast<const float4*>(Wrow + k * 256 + lane * 4);

    // stage x_0 (512 threads x float2 = 1024 floats, coalesced)
    {
        float2 v = *reinterpret_cast<const float2*>(Xb + tid * 2);
        *reinterpret_cast<float2*>(&xbuf[0][tid * 2]) = v;
    }
    __syncthreads();

    const float lr = 1.0f / 1024.0f;

    for (int t = 0; t < TT; ++t) {
        // issue next-step global load early (latency hides under compute)
        float2 vnext;
        if (t + 1 < TT)
            vnext = *reinterpret_cast<const float2*>(Xb + (t + 1) * NI + tid * 2);

        // lane's 16 x elements from LDS (ds_read_b128, conflict-free)
        const float* __restrict__ xc = xbuf[t & 1];
        float4 x[4];
#pragma unroll
        for (int k = 0; k < 4; ++k)
            x[k] = *reinterpret_cast<const float4*>(xc + k * 256 + lane * 4);

        // partial dot (16 elements per lane)
        float p = 0.0f;
#pragma unroll
        for (int k = 0; k < 4; ++k) {
            p = fmaf(w[k].x, x[k].x, p);
            p = fmaf(w[k].y, x[k].y, p);
            p = fmaf(w[k].z, x[k].z, p);
            p = fmaf(w[k].w, x[k].w, p);
        }

        // wave64 butterfly reduction
#pragma unroll
        for (int off = 32; off >= 1; off >>= 1)
            p += __shfl_xor(p, off, 64);

        const float y  = 1.0f / (1.0f + __expf(-p));
        const float c2 = lr * y;          // lr*y
        const float c1 = 1.0f - c2 * y;   // 1 - lr*y^2

        // W = W*c1 + c2*x
#pragma unroll
        for (int k = 0; k < 4; ++k) {
            w[k].x = fmaf(x[k].x, c2, w[k].x * c1);
            w[k].y = fmaf(x[k].y, c2, w[k].y * c1);
            w[k].z = fmaf(x[k].z, c2, w[k].z * c1);
            w[k].w = fmaf(x[k].w, c2, w[k].w * c1);
        }

        if (lane == 0)
            outb[t * NO + o] = y;

        // write-late: commit x_{t+1} to the other buffer, then barrier.
        // Safe: buf[(t+1)&1]'s last readers finished before the barrier
        // that ended iteration t-1.
        if (t + 1 < TT)
            *reinterpret_cast<float2*>(&xbuf[(t + 1) & 1][tid * 2]) = vnext;
        __syncthreads();
    }
}

extern "C" void kernel_launch(void* const* d_in, const int* in_sizes, int n_in,
                              void* d_out, int out_size, void* d_ws, size_t ws_size,
                              hipStream_t stream) {
    const float* X  = (const float*)d_in[0];   // [8][64][1024]
    const float* W0 = (const float*)d_in[1];   // [8][1024][1024]
    float* out = (float*)d_out;                // [8][64][1024]

    const int total_rows = BB * NO;                        // 8192
    const int blocks = total_rows / ROWS_PER_BLOCK;        // 1024
    oja_scan_kernel<<<blocks, ROWS_PER_BLOCK * 64, 0, stream>>>(X, W0, out);
}